// Round 9
// baseline (401.417 us; speedup 1.0000x reference)
//
#include <hip/hip_runtime.h>
#include <hip/hip_bf16.h>
#include <hip/hip_fp16.h>

#define N_NODES  50000
#define N_EDGES  800000
#define D        128
#define N_GRAPHS 64
#define CAP      64          // per-node bucket capacity; in-deg ~ Poisson(16)
#define EW_SCALE 1048576.0f  // 2^20 fixed-point for LDS degree accumulation
#define POOL_SPLIT 8
#define NB_GEMM1 391         // ceil(50000/128)
#define NB_P1    3125        // 800000/256
#define BIN_NODES 64         // nodes per bin (tgt>>6)
#define NBINS    782         // ceil(50000/64)
#define BINCAP   1536        // bin capacity; mean 1023, +16 sigma

__device__ __forceinline__ float2 h2f(unsigned int u) {
    __half2 h = *reinterpret_cast<__half2*>(&u);
    return __half22float2(h);
}
__device__ __forceinline__ unsigned int f2h(float a, float b) {
    __half2 h = __floats2half2_rn(a, b);
    return *reinterpret_cast<unsigned int*>(&h);
}

// ---------------------------------------------------------------------------
// FUSED: blocks [0,391) = gemm1 (fp32 x @ W1 -> fp16, unscaled);
//        blocks [391,3516) = phase-1 binning: append (src|tgtlo, ew) to bin
//        tgt>>6 via returning atomic on 782 L2-resident counters. Dense
//        appends merge in L2 -> no scattered-line write floor.
// ---------------------------------------------------------------------------
__global__ __launch_bounds__(256) void fused_gemm1_bin(const float* __restrict__ X,
                                                       const float* __restrict__ W,
                                                       __half* __restrict__ Yh,
                                                       const int* __restrict__ ei,
                                                       const float* __restrict__ ew,
                                                       int* __restrict__ bin_cnt,
                                                       uint2* __restrict__ binbuf) {
    __shared__ float XT[64 * 128];  // XT[k][r]
    __shared__ float Ws[64 * 128];  // Ws[k][c]

    if (blockIdx.x >= NB_GEMM1) {
        // ---- phase-1 binning branch ----
        int e = (blockIdx.x - NB_GEMM1) * 256 + threadIdx.x;
        if (e >= N_EDGES) return;
        int r = ei[e];
        int c = ei[N_EDGES + e];
        float w = ew[e];
        int bin = c >> 6;
        int pos = atomicAdd(&bin_cnt[bin], 1);
        if (pos < BINCAP)
            binbuf[(size_t)bin * BINCAP + pos] =
                make_uint2((unsigned)r | ((unsigned)(c & 63) << 16), __float_as_uint(w));
        return;
    }

    // ---- gemm branch: Y[n,128] = X[n,128] @ W[128,128], fp16 out ----
    const int tid  = threadIdx.x;
    const int row0 = blockIdx.x * 128;
    const int tr = tid >> 4, tc = tid & 15;
    float acc[8][8] = {};

    for (int kt = 0; kt < 2; kt++) {
        const int kbase = kt * 64;
        {
            const float4* src = (const float4*)(W + kbase * 128);
            float4* dst = (float4*)Ws;
            for (int i = tid; i < 2048; i += 256) dst[i] = src[i];
        }
        {
            int r  = tid >> 1;
            int rr = row0 + r; if (rr >= N_NODES) rr = N_NODES - 1;
            int k0 = (tid & 1) * 32;
            const float4* src = (const float4*)(X + (size_t)rr * 128 + kbase + k0);
#pragma unroll
            for (int i = 0; i < 8; i++) {
                float4 v = src[i];
                int k = k0 + i * 4;
                XT[(k + 0) * 128 + r] = v.x;
                XT[(k + 1) * 128 + r] = v.y;
                XT[(k + 2) * 128 + r] = v.z;
                XT[(k + 3) * 128 + r] = v.w;
            }
        }
        __syncthreads();
#pragma unroll 4
        for (int k = 0; k < 64; k++) {
            float xs[8], ws[8];
            *(float4*)&xs[0] = *(const float4*)(XT + k * 128 + tr * 8);
            *(float4*)&xs[4] = *(const float4*)(XT + k * 128 + tr * 8 + 4);
            *(float4*)&ws[0] = *(const float4*)(Ws + k * 128 + tc * 8);
            *(float4*)&ws[4] = *(const float4*)(Ws + k * 128 + tc * 8 + 4);
#pragma unroll
            for (int i = 0; i < 8; i++)
#pragma unroll
                for (int j = 0; j < 8; j++)
                    acc[i][j] += xs[i] * ws[j];
        }
        __syncthreads();
    }
#pragma unroll
    for (int i = 0; i < 8; i++) {
        int r = row0 + tr * 8 + i;
        if (r < N_NODES) {
            uint4 p;
            p.x = f2h(acc[i][0], acc[i][1]);
            p.y = f2h(acc[i][2], acc[i][3]);
            p.z = f2h(acc[i][4], acc[i][5]);
            p.w = f2h(acc[i][6], acc[i][7]);
            *(uint4*)(Yh + (size_t)r * 128 + tc * 8) = p;
        }
    }
}

// ---------------------------------------------------------------------------
// Phase 2: one block per bin. LDS scatter (fast LDS atomics) -> coalesced
// global writes of bucket/cnt/dinv. gstart folded in.
// ---------------------------------------------------------------------------
__global__ __launch_bounds__(256) void build_kernel(const uint2* __restrict__ binbuf,
                                                    const int* __restrict__ bin_cnt,
                                                    float2* __restrict__ bucket,
                                                    int* __restrict__ cnt,
                                                    float* __restrict__ dinv,
                                                    const int* __restrict__ batch,
                                                    int* __restrict__ gstart) {
    __shared__ unsigned int lcnt[BIN_NODES];
    __shared__ unsigned int ldeg[BIN_NODES];
    __shared__ uint2 lbuck[BIN_NODES * CAP];   // 32 KB

    const int bin = blockIdx.x;
    const int tid = threadIdx.x;
    if (tid < BIN_NODES) { lcnt[tid] = 0u; ldeg[tid] = 0u; }
    __syncthreads();

    int m = bin_cnt[bin]; if (m > BINCAP) m = BINCAP;
    for (int e = tid; e < m; e += 256) {
        uint2 v = binbuf[(size_t)bin * BINCAP + e];
        int tl = (v.x >> 16) & 63;
        float w = __uint_as_float(v.y);
        unsigned pos = atomicAdd(&lcnt[tl], 1u);
        if (pos < CAP) lbuck[tl * CAP + pos] = make_uint2(v.x & 0xFFFFu, v.y);
        atomicAdd(&ldeg[tl], (unsigned)(w * EW_SCALE + 0.5f));
    }
    __syncthreads();

    const int node0 = bin * BIN_NODES;
    if (tid < BIN_NODES) {
        int node = node0 + tid;
        if (node < N_NODES) {
            unsigned c = lcnt[tid]; if (c > CAP) c = CAP;
            cnt[node] = (int)c;
            dinv[node] = rsqrtf(1.0f + (float)ldeg[tid] * (1.0f / EW_SCALE));
            // gstart from sorted batch
            int a = batch[node];
            int p = (node == 0) ? -1 : batch[node - 1];
            for (int g = p + 1; g <= a; g++) gstart[g] = node;
            if (node == N_NODES - 1)
                for (int g = a + 1; g <= N_GRAPHS; g++) gstart[g] = N_NODES;
        }
    }
    // coalesced bucket write-out: wave w handles nodes w, w+4, ...
    int wave = tid >> 6, lane = tid & 63;
    for (int i = wave; i < BIN_NODES; i += 4) {
        int node = node0 + i;
        if (node >= N_NODES) break;
        unsigned c = lcnt[i]; if (c > CAP) c = CAP;
        if (lane < (int)c) {
            uint2 v = lbuck[i * CAP + lane];
            bucket[(size_t)node * CAP + lane] =
                make_float2(__int_as_float((int)v.x), __uint_as_float(v.y));
        }
    }
}

// x' = dinv[node] * x (fp16 in place, coalesced half2/thread)
__global__ __launch_bounds__(256) void scale_kernel(unsigned int* __restrict__ xh,
                                                    const float* __restrict__ dinv) {
    int idx = blockIdx.x * 256 + threadIdx.x;   // covers exactly N_NODES*64
    float dv = dinv[idx >> 6];
    float2 f = h2f(xh[idx]);
    xh[idx] = f2h(f.x * dv, f.y * dv);
}

// ---------------------------------------------------------------------------
// gemm2: Y = X(fp16) @ W(fp32), epilogue * dinv[row] -> fp16 (x2').
// ---------------------------------------------------------------------------
__global__ __launch_bounds__(256) void gemm128h2(const __half* __restrict__ Xh,
                                                 const float* __restrict__ W,
                                                 const float* __restrict__ dinv,
                                                 __half* __restrict__ Yh) {
    __shared__ float XT[64 * 128];
    __shared__ float Ws[64 * 128];
    const int tid  = threadIdx.x;
    const int row0 = blockIdx.x * 128;
    const int tr = tid >> 4, tc = tid & 15;
    float acc[8][8] = {};

    for (int kt = 0; kt < 2; kt++) {
        const int kbase = kt * 64;
        {
            const float4* src = (const float4*)(W + kbase * 128);
            float4* dst = (float4*)Ws;
            for (int i = tid; i < 2048; i += 256) dst[i] = src[i];
        }
        {
            int r  = tid >> 1;
            int rr = row0 + r; if (rr >= N_NODES) rr = N_NODES - 1;
            int k0 = (tid & 1) * 32;
            const unsigned int* src = (const unsigned int*)(Xh + (size_t)rr * 128 + kbase + k0);
#pragma unroll
            for (int i = 0; i < 16; i++) {
                float2 f = h2f(src[i]);
                int k = k0 + i * 2;
                XT[(k + 0) * 128 + r] = f.x;
                XT[(k + 1) * 128 + r] = f.y;
            }
        }
        __syncthreads();
#pragma unroll 4
        for (int k = 0; k < 64; k++) {
            float xs[8], ws[8];
            *(float4*)&xs[0] = *(const float4*)(XT + k * 128 + tr * 8);
            *(float4*)&xs[4] = *(const float4*)(XT + k * 128 + tr * 8 + 4);
            *(float4*)&ws[0] = *(const float4*)(Ws + k * 128 + tc * 8);
            *(float4*)&ws[4] = *(const float4*)(Ws + k * 128 + tc * 8 + 4);
#pragma unroll
            for (int i = 0; i < 8; i++)
#pragma unroll
                for (int j = 0; j < 8; j++)
                    acc[i][j] += xs[i] * ws[j];
        }
        __syncthreads();
    }
#pragma unroll
    for (int i = 0; i < 8; i++) {
        int r = row0 + tr * 8 + i;
        if (r < N_NODES) {
            float s = dinv[r];
            uint4 p;
            p.x = f2h(acc[i][0] * s, acc[i][1] * s);
            p.y = f2h(acc[i][2] * s, acc[i][3] * s);
            p.z = f2h(acc[i][4] * s, acc[i][5] * s);
            p.w = f2h(acc[i][6] * s, acc[i][7] * s);
            *(uint4*)(Yh + (size_t)r * 128 + tc * 8) = p;
        }
    }
}

// ---------------------------------------------------------------------------
// Bucket aggregation on pre-scaled features x' (fp16 in, fp16 out):
//   out[c] = relu( dinv[c]*(x'[c] + sum ew_i * x'[src_i]) + b )
// ---------------------------------------------------------------------------
__global__ __launch_bounds__(256) void agg_bucket_kernel(const __half* __restrict__ xwh,
                                                         const int* __restrict__ cnt,
                                                         const float2* __restrict__ bucket,
                                                         const float* __restrict__ dinv,
                                                         const float* __restrict__ bias,
                                                         __half* __restrict__ outh) {
    int node = blockIdx.x * 4 + (threadIdx.x >> 6);
    int lane = threadIdx.x & 63;
    const unsigned int* xh = (const unsigned int*)xwh;

    float dv = dinv[node];
    int n = cnt[node];

    float srcf = 0.0f, val = 0.0f;
    if (lane < n) {
        float2 eh = bucket[(size_t)node * CAP + lane];
        srcf = eh.x;
        val  = eh.y;                  // raw ew (features carry the dinv factors)
    }

    float2 xs = h2f(xh[(size_t)node * 64 + lane]);
    float accx = xs.x;
    float accy = xs.y;

    int i = 0;
    for (; i + 3 < n; i += 4) {
        int   r0 = __float_as_int(__shfl(srcf, i));
        int   r1 = __float_as_int(__shfl(srcf, i + 1));
        int   r2 = __float_as_int(__shfl(srcf, i + 2));
        int   r3 = __float_as_int(__shfl(srcf, i + 3));
        float v0 = __shfl(val, i);
        float v1 = __shfl(val, i + 1);
        float v2 = __shfl(val, i + 2);
        float v3 = __shfl(val, i + 3);
        float2 f0 = h2f(xh[(size_t)r0 * 64 + lane]);
        float2 f1 = h2f(xh[(size_t)r1 * 64 + lane]);
        float2 f2 = h2f(xh[(size_t)r2 * 64 + lane]);
        float2 f3 = h2f(xh[(size_t)r3 * 64 + lane]);
        accx += v0 * f0.x + v1 * f1.x + v2 * f2.x + v3 * f3.x;
        accy += v0 * f0.y + v1 * f1.y + v2 * f2.y + v3 * f3.y;
    }
    for (; i < n; i++) {
        int   r0 = __float_as_int(__shfl(srcf, i));
        float v0 = __shfl(val, i);
        float2 f0 = h2f(xh[(size_t)r0 * 64 + lane]);
        accx += v0 * f0.x;
        accy += v0 * f0.y;
    }

    float2 b = ((const float2*)bias)[lane];
    float ox = fmaxf(dv * accx + b.x, 0.0f);
    float oy = fmaxf(dv * accy + b.y, 0.0f);
    ((unsigned int*)outh)[(size_t)node * 64 + lane] = f2h(ox, oy);
}

// ---------------------------------------------------------------------------
// Pool (fp16 in): grid = graph x slice; unroll-4 ILP; LDS reduce; atomics.
// ---------------------------------------------------------------------------
__global__ __launch_bounds__(256) void pool_kernel(const __half* __restrict__ h,
                                                   const int* __restrict__ gstart,
                                                   float* __restrict__ pooled) {
    int g = blockIdx.x >> 3;
    int s = blockIdx.x & (POOL_SPLIT - 1);
    int a = gstart[g], b = gstart[g + 1];
    int len = b - a;
    int lo = a + (int)((long long)len * s / POOL_SPLIT);
    int hi = a + (int)((long long)len * (s + 1) / POOL_SPLIT);

    int d2 = threadIdx.x & 63;
    int nl = threadIdx.x >> 6;
    const unsigned int* h2 = (const unsigned int*)h;

    float accx = 0.0f, accy = 0.0f;
    int n = lo + nl;
    for (; n + 12 < hi; n += 16) {
        float2 v0 = h2f(h2[(size_t)n * 64 + d2]);
        float2 v1 = h2f(h2[(size_t)(n + 4) * 64 + d2]);
        float2 v2 = h2f(h2[(size_t)(n + 8) * 64 + d2]);
        float2 v3 = h2f(h2[(size_t)(n + 12) * 64 + d2]);
        accx += (v0.x + v1.x) + (v2.x + v3.x);
        accy += (v0.y + v1.y) + (v2.y + v3.y);
    }
    for (; n < hi; n += 4) {
        float2 v = h2f(h2[(size_t)n * 64 + d2]);
        accx += v.x; accy += v.y;
    }

    __shared__ float red[4][128];
    red[nl][d2 * 2]     = accx;
    red[nl][d2 * 2 + 1] = accy;
    __syncthreads();
    if (threadIdx.x < 128) {
        float v = red[0][threadIdx.x] + red[1][threadIdx.x]
                + red[2][threadIdx.x] + red[3][threadIdx.x];
        atomicAdd(&pooled[(size_t)g * 128 + threadIdx.x], v);
    }
}

__global__ __launch_bounds__(64) void final_kernel(const float* __restrict__ pooled,
                                                   const int* __restrict__ gstart,
                                                   const float* __restrict__ Wh,
                                                   const float* __restrict__ bh,
                                                   float* __restrict__ out) {
    int g = blockIdx.x;
    int t = threadIdx.x;
    float v = pooled[(size_t)g * 128 + t] * Wh[t]
            + pooled[(size_t)g * 128 + 64 + t] * Wh[64 + t];
#pragma unroll
    for (int off = 32; off > 0; off >>= 1) v += __shfl_down(v, off, 64);
    if (t == 0) {
        float cntf = (float)(gstart[g + 1] - gstart[g]);
        out[g] = v / fmaxf(cntf, 1.0f) + bh[0];
    }
}

// ---------------------------------------------------------------------------
extern "C" void kernel_launch(void* const* d_in, const int* in_sizes, int n_in,
                              void* d_out, int out_size, void* d_ws, size_t ws_size,
                              hipStream_t stream) {
    const float* x   = (const float*)d_in[0];
    const float* ew  = (const float*)d_in[1];
    const float* W1  = (const float*)d_in[2];
    const float* b1  = (const float*)d_in[3];
    const float* W2  = (const float*)d_in[4];
    const float* b2  = (const float*)d_in[5];
    const float* Wh  = (const float*)d_in[6];
    const float* bh  = (const float*)d_in[7];
    const int*   ei  = (const int*)d_in[8];
    const int*   bat = (const int*)d_in[9];
    float* out = (float*)d_out;

    char* ws = (char*)d_ws;
    __half* bufAh  = (__half*)ws;                         ws += (size_t)N_NODES * D * 2;
    __half* bufBh  = (__half*)ws;                         ws += (size_t)N_NODES * D * 2;
    float2* bucket = (float2*)ws;                         ws += (size_t)N_NODES * CAP * 8;
    uint2*  binbuf = (uint2*)ws;                          ws += (size_t)NBINS * BINCAP * 8;
    int*    bin_cnt= (int*)ws;                            ws += (size_t)NBINS * 4;
    float*  dinv   = (float*)ws;                          ws += (size_t)N_NODES * 4;
    int*    cnt    = (int*)ws;                            ws += (size_t)N_NODES * 4;
    int*    gstart = (int*)ws;                            ws += (N_GRAPHS + 1) * 4;
    float*  pooled = (float*)ws;                          ws += (size_t)N_GRAPHS * D * 4;

    const int nb_gemm  = (N_NODES + 127) / 128;       // 391
    const int nb_agg   = N_NODES / 4;                 // 12500 (exact)
    const int nb_scale = N_NODES * 64 / 256;          // 12500 (exact)
    const int nb_pool  = N_GRAPHS * POOL_SPLIT;       // 512

    // --- zero bin counters / pool accumulator ---
    hipMemsetAsync(bin_cnt, 0, (size_t)NBINS * 4, stream);
    hipMemsetAsync(pooled, 0, (size_t)N_GRAPHS * D * 4, stream);

    // --- fused: gemm1 (x@W1 -> fp16) overlapped with phase-1 binning ---
    fused_gemm1_bin<<<NB_GEMM1 + NB_P1, 256, 0, stream>>>(x, W1, bufAh, ei, ew, bin_cnt, binbuf);

    // --- phase 2: LDS-bucket build (+ cnt/dinv/gstart) ---
    build_kernel<<<NBINS, 256, 0, stream>>>(binbuf, bin_cnt, bucket, cnt, dinv, bat, gstart);

    // --- layer 1 ---
    scale_kernel<<<nb_scale, 256, 0, stream>>>((unsigned int*)bufAh, dinv);
    agg_bucket_kernel<<<nb_agg, 256, 0, stream>>>(bufAh, cnt, bucket, dinv, b1, bufBh);

    // --- layer 2 ---
    gemm128h2<<<nb_gemm, 256, 0, stream>>>(bufBh, W2, dinv, bufAh);
    agg_bucket_kernel<<<nb_agg, 256, 0, stream>>>(bufAh, cnt, bucket, dinv, b2, bufBh);

    // --- pool + head ---
    pool_kernel<<<nb_pool, 256, 0, stream>>>(bufBh, gstart, pooled);
    final_kernel<<<N_GRAPHS, 64, 0, stream>>>(pooled, gstart, Wh, bh, out);
}

// Round 10
// 264.490 us; speedup vs baseline: 1.5177x; 1.5177x over previous
//
#include <hip/hip_runtime.h>
#include <hip/hip_bf16.h>
#include <hip/hip_fp16.h>

#define N_NODES  50000
#define N_EDGES  800000
#define D        128
#define N_GRAPHS 64
#define CAP      64          // bucket capacity; in-deg ~ Poisson(16), P(>=64) ~ 1e-19
#define EW_SCALE 1048576.0f  // 2^20 fixed-point for packed weighted-degree
#define POOL_SPLIT 8
#define NB_GEMM1 391         // ceil(50000/128)
#define NB_FILL  3125        // 800000/256

__device__ __forceinline__ float2 h2f(unsigned int u) {
    __half2 h = *reinterpret_cast<__half2*>(&u);
    return __half22float2(h);
}
__device__ __forceinline__ unsigned int f2h(float a, float b) {
    __half2 h = __floats2half2_rn(a, b);
    return *reinterpret_cast<unsigned int*>(&h);
}
__device__ __forceinline__ float hu2f(unsigned short u) {
    __half_raw hr; hr.x = u;
    return __half2float(__half(hr));
}

// ---------------------------------------------------------------------------
// FUSED: blocks [0,391) = gemm1 (fp32 x @ W1 -> fp16, unscaled);
//        blocks [391,3516) = fill: 1 edge/thread, ONE returning 64-bit atomic
//        per edge on 50K spread counters (r9 lesson: few counters = per-addr
//        serialization disaster; 50K is the sweet spot). Bucket entry is 4B:
//        src:u16 | ew:fp16.
// ---------------------------------------------------------------------------
__global__ __launch_bounds__(256) void fused_gemm1_fill(const float* __restrict__ X,
                                                        const float* __restrict__ W,
                                                        __half* __restrict__ Yh,
                                                        const int* __restrict__ ei,
                                                        const float* __restrict__ ew,
                                                        unsigned long long* __restrict__ packed,
                                                        unsigned int* __restrict__ bucket) {
    __shared__ float XT[64 * 128];  // XT[k][r]
    __shared__ float Ws[64 * 128];  // Ws[k][c]

    if (blockIdx.x >= NB_GEMM1) {
        // ---- fill branch ----
        int e = (blockIdx.x - NB_GEMM1) * 256 + threadIdx.x;
        if (e >= N_EDGES) return;
        int r = ei[e];
        int c = ei[N_EDGES + e];
        float w = ew[e];
        unsigned long long add = (1ULL << 40) | (unsigned long long)(unsigned)(w * EW_SCALE + 0.5f);
        unsigned long long old = atomicAdd(&packed[c], add);
        unsigned pos = (unsigned)(old >> 40);
        if (pos < CAP) {
            unsigned short wh = __half_as_ushort(__float2half_rn(w));
            bucket[(size_t)c * CAP + pos] = (unsigned)r | ((unsigned)wh << 16);
        }
        return;
    }

    // ---- gemm branch: Y[n,128] = X[n,128] @ W[128,128], fp16 out ----
    const int tid  = threadIdx.x;
    const int row0 = blockIdx.x * 128;
    const int tr = tid >> 4, tc = tid & 15;
    float acc[8][8] = {};

    for (int kt = 0; kt < 2; kt++) {
        const int kbase = kt * 64;
        {
            const float4* src = (const float4*)(W + kbase * 128);
            float4* dst = (float4*)Ws;
            for (int i = tid; i < 2048; i += 256) dst[i] = src[i];
        }
        {
            int r  = tid >> 1;
            int rr = row0 + r; if (rr >= N_NODES) rr = N_NODES - 1;
            int k0 = (tid & 1) * 32;
            const float4* src = (const float4*)(X + (size_t)rr * 128 + kbase + k0);
#pragma unroll
            for (int i = 0; i < 8; i++) {
                float4 v = src[i];
                int k = k0 + i * 4;
                XT[(k + 0) * 128 + r] = v.x;
                XT[(k + 1) * 128 + r] = v.y;
                XT[(k + 2) * 128 + r] = v.z;
                XT[(k + 3) * 128 + r] = v.w;
            }
        }
        __syncthreads();
#pragma unroll 4
        for (int k = 0; k < 64; k++) {
            float xs[8], ws[8];
            *(float4*)&xs[0] = *(const float4*)(XT + k * 128 + tr * 8);
            *(float4*)&xs[4] = *(const float4*)(XT + k * 128 + tr * 8 + 4);
            *(float4*)&ws[0] = *(const float4*)(Ws + k * 128 + tc * 8);
            *(float4*)&ws[4] = *(const float4*)(Ws + k * 128 + tc * 8 + 4);
#pragma unroll
            for (int i = 0; i < 8; i++)
#pragma unroll
                for (int j = 0; j < 8; j++)
                    acc[i][j] += xs[i] * ws[j];
        }
        __syncthreads();
    }
#pragma unroll
    for (int i = 0; i < 8; i++) {
        int r = row0 + tr * 8 + i;
        if (r < N_NODES) {
            uint4 p;
            p.x = f2h(acc[i][0], acc[i][1]);
            p.y = f2h(acc[i][2], acc[i][3]);
            p.z = f2h(acc[i][4], acc[i][5]);
            p.w = f2h(acc[i][6], acc[i][7]);
            *(uint4*)(Yh + (size_t)r * 128 + tc * 8) = p;
        }
    }
}

// ---------------------------------------------------------------------------
// dinv/cnt/gstart unpack + in-place feature prescale x' = dinv*x (fused).
// Block covers 256 nodes; dinv cached in LDS; scale loop is coalesced.
// ---------------------------------------------------------------------------
__global__ __launch_bounds__(256) void dinv_scale_kernel(const unsigned long long* __restrict__ packed,
                                                         int* __restrict__ cnt, float* __restrict__ dinv,
                                                         const int* __restrict__ batch,
                                                         int* __restrict__ gstart,
                                                         unsigned int* __restrict__ xh) {
    __shared__ float sdv[256];
    const int node0 = blockIdx.x * 256;
    const int i = node0 + threadIdx.x;
    float dv = 1.0f;
    if (i < N_NODES) {
        unsigned long long p = packed[i];
        int c = (int)(p >> 40);
        cnt[i] = c < CAP ? c : CAP;
        dv = rsqrtf(1.0f + (float)(p & 0xFFFFFFFFFFULL) * (1.0f / EW_SCALE));
        dinv[i] = dv;
        int a = batch[i];
        int pg = (i == 0) ? -1 : batch[i - 1];
        for (int g = pg + 1; g <= a; g++) gstart[g] = i;
        if (i == N_NODES - 1)
            for (int g = a + 1; g <= N_GRAPHS; g++) gstart[g] = N_NODES;
    }
    sdv[threadIdx.x] = dv;
    __syncthreads();
    const size_t base = (size_t)node0 * 64;
    int nn = N_NODES - node0; if (nn > 256) nn = 256;
    const int total = nn * 64;
    for (int j = threadIdx.x; j < total; j += 256) {
        float d = sdv[j >> 6];
        float2 f = h2f(xh[base + j]);
        xh[base + j] = f2h(f.x * d, f.y * d);
    }
}

// ---------------------------------------------------------------------------
// gemm2: Y = X(fp16) @ W(fp32), epilogue * dinv[row] -> fp16 (pre-scaled x2').
// ---------------------------------------------------------------------------
__global__ __launch_bounds__(256) void gemm128h2(const __half* __restrict__ Xh,
                                                 const float* __restrict__ W,
                                                 const float* __restrict__ dinv,
                                                 __half* __restrict__ Yh) {
    __shared__ float XT[64 * 128];
    __shared__ float Ws[64 * 128];
    const int tid  = threadIdx.x;
    const int row0 = blockIdx.x * 128;
    const int tr = tid >> 4, tc = tid & 15;
    float acc[8][8] = {};

    for (int kt = 0; kt < 2; kt++) {
        const int kbase = kt * 64;
        {
            const float4* src = (const float4*)(W + kbase * 128);
            float4* dst = (float4*)Ws;
            for (int i = tid; i < 2048; i += 256) dst[i] = src[i];
        }
        {
            int r  = tid >> 1;
            int rr = row0 + r; if (rr >= N_NODES) rr = N_NODES - 1;
            int k0 = (tid & 1) * 32;
            const unsigned int* src = (const unsigned int*)(Xh + (size_t)rr * 128 + kbase + k0);
#pragma unroll
            for (int i = 0; i < 16; i++) {
                float2 f = h2f(src[i]);
                int k = k0 + i * 2;
                XT[(k + 0) * 128 + r] = f.x;
                XT[(k + 1) * 128 + r] = f.y;
            }
        }
        __syncthreads();
#pragma unroll 4
        for (int k = 0; k < 64; k++) {
            float xs[8], ws[8];
            *(float4*)&xs[0] = *(const float4*)(XT + k * 128 + tr * 8);
            *(float4*)&xs[4] = *(const float4*)(XT + k * 128 + tr * 8 + 4);
            *(float4*)&ws[0] = *(const float4*)(Ws + k * 128 + tc * 8);
            *(float4*)&ws[4] = *(const float4*)(Ws + k * 128 + tc * 8 + 4);
#pragma unroll
            for (int i = 0; i < 8; i++)
#pragma unroll
                for (int j = 0; j < 8; j++)
                    acc[i][j] += xs[i] * ws[j];
        }
        __syncthreads();
    }
#pragma unroll
    for (int i = 0; i < 8; i++) {
        int r = row0 + tr * 8 + i;
        if (r < N_NODES) {
            float s = dinv[r];
            uint4 p;
            p.x = f2h(acc[i][0] * s, acc[i][1] * s);
            p.y = f2h(acc[i][2] * s, acc[i][3] * s);
            p.z = f2h(acc[i][4] * s, acc[i][5] * s);
            p.w = f2h(acc[i][6] * s, acc[i][7] * s);
            *(uint4*)(Yh + (size_t)r * 128 + tc * 8) = p;
        }
    }
}

// ---------------------------------------------------------------------------
// Bucket aggregation on pre-scaled features x' (fp16 in, fp16 out):
//   out[c] = relu( dinv[c]*(x'[c] + sum ew_i * x'[src_i]) + b )
// 4B bucket entries; ONE shfl per edge (decode src/ew after broadcast).
// ---------------------------------------------------------------------------
__global__ __launch_bounds__(256) void agg_bucket_kernel(const __half* __restrict__ xwh,
                                                         const int* __restrict__ cnt,
                                                         const unsigned int* __restrict__ bucket,
                                                         const float* __restrict__ dinv,
                                                         const float* __restrict__ bias,
                                                         __half* __restrict__ outh) {
    int node = blockIdx.x * 4 + (threadIdx.x >> 6);
    int lane = threadIdx.x & 63;
    const unsigned int* xh = (const unsigned int*)xwh;

    float dv = dinv[node];
    int n = cnt[node];

    unsigned int ehdr = (lane < n) ? bucket[(size_t)node * CAP + lane] : 0u;
    int   eh = (int)ehdr;   // shfl on int

    float2 xs = h2f(xh[(size_t)node * 64 + lane]);
    float accx = xs.x;
    float accy = xs.y;

    int i = 0;
    for (; i + 3 < n; i += 4) {
        unsigned v0u = (unsigned)__shfl(eh, i);
        unsigned v1u = (unsigned)__shfl(eh, i + 1);
        unsigned v2u = (unsigned)__shfl(eh, i + 2);
        unsigned v3u = (unsigned)__shfl(eh, i + 3);
        int r0 = v0u & 0xFFFF, r1 = v1u & 0xFFFF, r2 = v2u & 0xFFFF, r3 = v3u & 0xFFFF;
        float v0 = hu2f((unsigned short)(v0u >> 16));
        float v1 = hu2f((unsigned short)(v1u >> 16));
        float v2 = hu2f((unsigned short)(v2u >> 16));
        float v3 = hu2f((unsigned short)(v3u >> 16));
        float2 f0 = h2f(xh[(size_t)r0 * 64 + lane]);
        float2 f1 = h2f(xh[(size_t)r1 * 64 + lane]);
        float2 f2 = h2f(xh[(size_t)r2 * 64 + lane]);
        float2 f3 = h2f(xh[(size_t)r3 * 64 + lane]);
        accx += v0 * f0.x + v1 * f1.x + v2 * f2.x + v3 * f3.x;
        accy += v0 * f0.y + v1 * f1.y + v2 * f2.y + v3 * f3.y;
    }
    for (; i < n; i++) {
        unsigned v0u = (unsigned)__shfl(eh, i);
        int r0 = v0u & 0xFFFF;
        float v0 = hu2f((unsigned short)(v0u >> 16));
        float2 f0 = h2f(xh[(size_t)r0 * 64 + lane]);
        accx += v0 * f0.x;
        accy += v0 * f0.y;
    }

    float2 b = ((const float2*)bias)[lane];
    float ox = fmaxf(dv * accx + b.x, 0.0f);
    float oy = fmaxf(dv * accy + b.y, 0.0f);
    ((unsigned int*)outh)[(size_t)node * 64 + lane] = f2h(ox, oy);
}

// ---------------------------------------------------------------------------
// Pool (fp16 in): grid = graph x slice; unroll-4 ILP; LDS reduce; atomics.
// ---------------------------------------------------------------------------
__global__ __launch_bounds__(256) void pool_kernel(const __half* __restrict__ h,
                                                   const int* __restrict__ gstart,
                                                   float* __restrict__ pooled) {
    int g = blockIdx.x >> 3;
    int s = blockIdx.x & (POOL_SPLIT - 1);
    int a = gstart[g], b = gstart[g + 1];
    int len = b - a;
    int lo = a + (int)((long long)len * s / POOL_SPLIT);
    int hi = a + (int)((long long)len * (s + 1) / POOL_SPLIT);

    int d2 = threadIdx.x & 63;
    int nl = threadIdx.x >> 6;
    const unsigned int* h2 = (const unsigned int*)h;

    float accx = 0.0f, accy = 0.0f;
    int n = lo + nl;
    for (; n + 12 < hi; n += 16) {
        float2 v0 = h2f(h2[(size_t)n * 64 + d2]);
        float2 v1 = h2f(h2[(size_t)(n + 4) * 64 + d2]);
        float2 v2 = h2f(h2[(size_t)(n + 8) * 64 + d2]);
        float2 v3 = h2f(h2[(size_t)(n + 12) * 64 + d2]);
        accx += (v0.x + v1.x) + (v2.x + v3.x);
        accy += (v0.y + v1.y) + (v2.y + v3.y);
    }
    for (; n < hi; n += 4) {
        float2 v = h2f(h2[(size_t)n * 64 + d2]);
        accx += v.x; accy += v.y;
    }

    __shared__ float red[4][128];
    red[nl][d2 * 2]     = accx;
    red[nl][d2 * 2 + 1] = accy;
    __syncthreads();
    if (threadIdx.x < 128) {
        float v = red[0][threadIdx.x] + red[1][threadIdx.x]
                + red[2][threadIdx.x] + red[3][threadIdx.x];
        atomicAdd(&pooled[(size_t)g * 128 + threadIdx.x], v);
    }
}

__global__ __launch_bounds__(64) void final_kernel(const float* __restrict__ pooled,
                                                   const int* __restrict__ gstart,
                                                   const float* __restrict__ Wh,
                                                   const float* __restrict__ bh,
                                                   float* __restrict__ out) {
    int g = blockIdx.x;
    int t = threadIdx.x;
    float v = pooled[(size_t)g * 128 + t] * Wh[t]
            + pooled[(size_t)g * 128 + 64 + t] * Wh[64 + t];
#pragma unroll
    for (int off = 32; off > 0; off >>= 1) v += __shfl_down(v, off, 64);
    if (t == 0) {
        float cntf = (float)(gstart[g + 1] - gstart[g]);
        out[g] = v / fmaxf(cntf, 1.0f) + bh[0];
    }
}

// ---------------------------------------------------------------------------
extern "C" void kernel_launch(void* const* d_in, const int* in_sizes, int n_in,
                              void* d_out, int out_size, void* d_ws, size_t ws_size,
                              hipStream_t stream) {
    const float* x   = (const float*)d_in[0];
    const float* ew  = (const float*)d_in[1];
    const float* W1  = (const float*)d_in[2];
    const float* b1  = (const float*)d_in[3];
    const float* W2  = (const float*)d_in[4];
    const float* b2  = (const float*)d_in[5];
    const float* Wh  = (const float*)d_in[6];
    const float* bh  = (const float*)d_in[7];
    const int*   ei  = (const int*)d_in[8];
    const int*   bat = (const int*)d_in[9];
    float* out = (float*)d_out;

    char* ws = (char*)d_ws;
    __half* bufAh  = (__half*)ws;                         ws += (size_t)N_NODES * D * 2;
    __half* bufBh  = (__half*)ws;                         ws += (size_t)N_NODES * D * 2;
    unsigned int* bucket = (unsigned int*)ws;             ws += (size_t)N_NODES * CAP * 4;
    unsigned long long* packed = (unsigned long long*)ws; ws += (size_t)N_NODES * 8;
    float*  dinv   = (float*)ws;                          ws += (size_t)N_NODES * 4;
    int*    cnt    = (int*)ws;                            ws += (size_t)N_NODES * 4;
    int*    gstart = (int*)ws;                            ws += (N_GRAPHS + 1) * 4;
    float*  pooled = (float*)ws;                          ws += (size_t)N_GRAPHS * D * 4;

    const int nb_nodes = (N_NODES + 255) / 256;       // 196
    const int nb_gemm  = (N_NODES + 127) / 128;       // 391
    const int nb_agg   = N_NODES / 4;                 // 12500 (exact)
    const int nb_pool  = N_GRAPHS * POOL_SPLIT;       // 512

    // --- zero counters / pool accumulator ---
    hipMemsetAsync(packed, 0, (size_t)N_NODES * 8, stream);
    hipMemsetAsync(pooled, 0, (size_t)N_GRAPHS * D * 4, stream);

    // --- fused: gemm1 (x@W1 -> fp16) overlapped with fill (atomic-bound) ---
    fused_gemm1_fill<<<NB_GEMM1 + NB_FILL, 256, 0, stream>>>(x, W1, bufAh, ei, ew, packed, bucket);

    // --- unpack + prescale (single kernel) ---
    dinv_scale_kernel<<<nb_nodes, 256, 0, stream>>>(packed, cnt, dinv, bat, gstart,
                                                    (unsigned int*)bufAh);

    // --- layer 1 agg ---
    agg_bucket_kernel<<<nb_agg, 256, 0, stream>>>(bufAh, cnt, bucket, dinv, b1, bufBh);

    // --- layer 2 ---
    gemm128h2<<<nb_gemm, 256, 0, stream>>>(bufBh, W2, dinv, bufAh);
    agg_bucket_kernel<<<nb_agg, 256, 0, stream>>>(bufAh, cnt, bucket, dinv, b2, bufBh);

    // --- pool + head ---
    pool_kernel<<<nb_pool, 256, 0, stream>>>(bufBh, gstart, pooled);
    final_kernel<<<N_GRAPHS, 64, 0, stream>>>(pooled, gstart, Wh, bh, out);
}

// Round 11
// 254.707 us; speedup vs baseline: 1.5760x; 1.0384x over previous
//
#include <hip/hip_runtime.h>
#include <hip/hip_bf16.h>
#include <hip/hip_fp16.h>

#define N_NODES  50000
#define N_EDGES  800000
#define D        128
#define N_GRAPHS 64
#define CAP      64          // bucket capacity; in-deg ~ Poisson(16), P(>=64) ~ 1e-19
#define EW_SCALE 1048576.0f  // 2^20 fixed-point for packed weighted-degree
#define POOL_SPLIT 8
#define NB_GEMM1 391         // ceil(50000/128)
#define NB_FILL  3125        // 800000/256

__device__ __forceinline__ float2 h2f(unsigned int u) {
    __half2 h = *reinterpret_cast<__half2*>(&u);
    return __half22float2(h);
}
__device__ __forceinline__ unsigned int f2h(float a, float b) {
    __half2 h = __floats2half2_rn(a, b);
    return *reinterpret_cast<unsigned int*>(&h);
}
__device__ __forceinline__ float hu2f(unsigned short u) {
    __half_raw hr; hr.x = u;
    return __half2float(__half(hr));
}

// ---------------------------------------------------------------------------
// FUSED: blocks [0,391) = gemm1 (fp32 x @ W1 -> fp16, BK=32 so LDS=32KB ->
//        5 blocks/CU, raising fill-branch occupancy to ~40%);
//        blocks [391,3516) = fill: 1 edge/thread, ONE returning 64-bit atomic
//        per edge on 50K spread counters. Bucket entry 4B: src:u16 | ew:fp16.
// ---------------------------------------------------------------------------
__global__ __launch_bounds__(256) void fused_gemm1_fill(const float* __restrict__ X,
                                                        const float* __restrict__ W,
                                                        __half* __restrict__ Yh,
                                                        const int* __restrict__ ei,
                                                        const float* __restrict__ ew,
                                                        unsigned long long* __restrict__ packed,
                                                        unsigned int* __restrict__ bucket) {
    __shared__ float XT[32 * 128];  // XT[k][r]  16 KB
    __shared__ float Ws[32 * 128];  // Ws[k][c]  16 KB

    if (blockIdx.x >= NB_GEMM1) {
        // ---- fill branch ----
        int e = (blockIdx.x - NB_GEMM1) * 256 + threadIdx.x;
        if (e >= N_EDGES) return;
        int r = ei[e];
        int c = ei[N_EDGES + e];
        float w = ew[e];
        unsigned long long add = (1ULL << 40) | (unsigned long long)(unsigned)(w * EW_SCALE + 0.5f);
        unsigned long long old = atomicAdd(&packed[c], add);
        unsigned pos = (unsigned)(old >> 40);
        if (pos < CAP) {
            unsigned short wh = __half_as_ushort(__float2half_rn(w));
            bucket[(size_t)c * CAP + pos] = (unsigned)r | ((unsigned)wh << 16);
        }
        return;
    }

    // ---- gemm branch: Y[n,128] = X[n,128] @ W[128,128], fp16 out, BK=32 ----
    const int tid  = threadIdx.x;
    const int row0 = blockIdx.x * 128;
    const int tr = tid >> 4, tc = tid & 15;
    float acc[8][8] = {};

    for (int kt = 0; kt < 4; kt++) {
        const int kbase = kt * 32;
        {   // stage W[kbase:kbase+32, :]  (4096 floats = 1024 float4)
            const float4* src = (const float4*)(W + kbase * 128);
            float4* dst = (float4*)Ws;
            for (int i = tid; i < 1024; i += 256) dst[i] = src[i];
        }
        {   // stage X^T chunk: thread covers row tid>>1, k-half (tid&1)*16
            int r  = tid >> 1;
            int rr = row0 + r; if (rr >= N_NODES) rr = N_NODES - 1;
            int k0 = (tid & 1) * 16;
            const float4* src = (const float4*)(X + (size_t)rr * 128 + kbase + k0);
#pragma unroll
            for (int i = 0; i < 4; i++) {
                float4 v = src[i];
                int k = k0 + i * 4;
                XT[(k + 0) * 128 + r] = v.x;
                XT[(k + 1) * 128 + r] = v.y;
                XT[(k + 2) * 128 + r] = v.z;
                XT[(k + 3) * 128 + r] = v.w;
            }
        }
        __syncthreads();
#pragma unroll 4
        for (int k = 0; k < 32; k++) {
            float xs[8], ws[8];
            *(float4*)&xs[0] = *(const float4*)(XT + k * 128 + tr * 8);
            *(float4*)&xs[4] = *(const float4*)(XT + k * 128 + tr * 8 + 4);
            *(float4*)&ws[0] = *(const float4*)(Ws + k * 128 + tc * 8);
            *(float4*)&ws[4] = *(const float4*)(Ws + k * 128 + tc * 8 + 4);
#pragma unroll
            for (int i = 0; i < 8; i++)
#pragma unroll
                for (int j = 0; j < 8; j++)
                    acc[i][j] += xs[i] * ws[j];
        }
        __syncthreads();
    }
#pragma unroll
    for (int i = 0; i < 8; i++) {
        int r = row0 + tr * 8 + i;
        if (r < N_NODES) {
            uint4 p;
            p.x = f2h(acc[i][0], acc[i][1]);
            p.y = f2h(acc[i][2], acc[i][3]);
            p.z = f2h(acc[i][4], acc[i][5]);
            p.w = f2h(acc[i][6], acc[i][7]);
            *(uint4*)(Yh + (size_t)r * 128 + tc * 8) = p;
        }
    }
}

// ---------------------------------------------------------------------------
// unpack cnt/dinv + graph starts from sorted batch (r8 structure)
// ---------------------------------------------------------------------------
__global__ void dinv_gstart_kernel(const unsigned long long* __restrict__ packed,
                                   int* __restrict__ cnt, float* __restrict__ dinv,
                                   const int* __restrict__ batch, int* __restrict__ gstart) {
    int i = blockIdx.x * 256 + threadIdx.x;
    if (i >= N_NODES) return;
    unsigned long long p = packed[i];
    int c = (int)(p >> 40);
    cnt[i] = c < CAP ? c : CAP;
    float deg = 1.0f + (float)(p & 0xFFFFFFFFFFULL) * (1.0f / EW_SCALE);
    dinv[i] = rsqrtf(deg);

    int a = batch[i];
    if (i == 0) {
        for (int g = 0; g <= a; g++) gstart[g] = 0;
    } else {
        int pg = batch[i - 1];
        for (int g = pg + 1; g <= a; g++) gstart[g] = i;
    }
    if (i == N_NODES - 1) {
        for (int g = a + 1; g <= N_GRAPHS; g++) gstart[g] = N_NODES;
    }
}

// x' = dinv[node] * x (fp16 in place, coalesced half2/thread, 12500 blocks)
__global__ __launch_bounds__(256) void scale_kernel(unsigned int* __restrict__ xh,
                                                    const float* __restrict__ dinv) {
    int idx = blockIdx.x * 256 + threadIdx.x;   // covers exactly N_NODES*64
    float dv = dinv[idx >> 6];
    float2 f = h2f(xh[idx]);
    xh[idx] = f2h(f.x * dv, f.y * dv);
}

// ---------------------------------------------------------------------------
// gemm2: Y = X(fp16) @ W(fp32), epilogue * dinv[row] -> fp16 (pre-scaled x2').
// ---------------------------------------------------------------------------
__global__ __launch_bounds__(256) void gemm128h2(const __half* __restrict__ Xh,
                                                 const float* __restrict__ W,
                                                 const float* __restrict__ dinv,
                                                 __half* __restrict__ Yh) {
    __shared__ float XT[64 * 128];
    __shared__ float Ws[64 * 128];
    const int tid  = threadIdx.x;
    const int row0 = blockIdx.x * 128;
    const int tr = tid >> 4, tc = tid & 15;
    float acc[8][8] = {};

    for (int kt = 0; kt < 2; kt++) {
        const int kbase = kt * 64;
        {
            const float4* src = (const float4*)(W + kbase * 128);
            float4* dst = (float4*)Ws;
            for (int i = tid; i < 2048; i += 256) dst[i] = src[i];
        }
        {
            int r  = tid >> 1;
            int rr = row0 + r; if (rr >= N_NODES) rr = N_NODES - 1;
            int k0 = (tid & 1) * 32;
            const unsigned int* src = (const unsigned int*)(Xh + (size_t)rr * 128 + kbase + k0);
#pragma unroll
            for (int i = 0; i < 16; i++) {
                float2 f = h2f(src[i]);
                int k = k0 + i * 2;
                XT[(k + 0) * 128 + r] = f.x;
                XT[(k + 1) * 128 + r] = f.y;
            }
        }
        __syncthreads();
#pragma unroll 4
        for (int k = 0; k < 64; k++) {
            float xs[8], ws[8];
            *(float4*)&xs[0] = *(const float4*)(XT + k * 128 + tr * 8);
            *(float4*)&xs[4] = *(const float4*)(XT + k * 128 + tr * 8 + 4);
            *(float4*)&ws[0] = *(const float4*)(Ws + k * 128 + tc * 8);
            *(float4*)&ws[4] = *(const float4*)(Ws + k * 128 + tc * 8 + 4);
#pragma unroll
            for (int i = 0; i < 8; i++)
#pragma unroll
                for (int j = 0; j < 8; j++)
                    acc[i][j] += xs[i] * ws[j];
        }
        __syncthreads();
    }
#pragma unroll
    for (int i = 0; i < 8; i++) {
        int r = row0 + tr * 8 + i;
        if (r < N_NODES) {
            float s = dinv[r];
            uint4 p;
            p.x = f2h(acc[i][0] * s, acc[i][1] * s);
            p.y = f2h(acc[i][2] * s, acc[i][3] * s);
            p.z = f2h(acc[i][4] * s, acc[i][5] * s);
            p.w = f2h(acc[i][6] * s, acc[i][7] * s);
            *(uint4*)(Yh + (size_t)r * 128 + tc * 8) = p;
        }
    }
}

// ---------------------------------------------------------------------------
// Bucket aggregation on pre-scaled features x' (fp16 in, fp16 out):
//   out[c] = relu( dinv[c]*(x'[c] + sum ew_i * x'[src_i]) + b )
// 4B bucket entries; ONE shfl per edge (decode src/ew after broadcast).
// ---------------------------------------------------------------------------
__global__ __launch_bounds__(256) void agg_bucket_kernel(const __half* __restrict__ xwh,
                                                         const int* __restrict__ cnt,
                                                         const unsigned int* __restrict__ bucket,
                                                         const float* __restrict__ dinv,
                                                         const float* __restrict__ bias,
                                                         __half* __restrict__ outh) {
    int node = blockIdx.x * 4 + (threadIdx.x >> 6);
    int lane = threadIdx.x & 63;
    const unsigned int* xh = (const unsigned int*)xwh;

    float dv = dinv[node];
    int n = cnt[node];

    unsigned int ehdr = (lane < n) ? bucket[(size_t)node * CAP + lane] : 0u;
    int   eh = (int)ehdr;   // shfl on int

    float2 xs = h2f(xh[(size_t)node * 64 + lane]);
    float accx = xs.x;
    float accy = xs.y;

    int i = 0;
    for (; i + 3 < n; i += 4) {
        unsigned v0u = (unsigned)__shfl(eh, i);
        unsigned v1u = (unsigned)__shfl(eh, i + 1);
        unsigned v2u = (unsigned)__shfl(eh, i + 2);
        unsigned v3u = (unsigned)__shfl(eh, i + 3);
        int r0 = v0u & 0xFFFF, r1 = v1u & 0xFFFF, r2 = v2u & 0xFFFF, r3 = v3u & 0xFFFF;
        float v0 = hu2f((unsigned short)(v0u >> 16));
        float v1 = hu2f((unsigned short)(v1u >> 16));
        float v2 = hu2f((unsigned short)(v2u >> 16));
        float v3 = hu2f((unsigned short)(v3u >> 16));
        float2 f0 = h2f(xh[(size_t)r0 * 64 + lane]);
        float2 f1 = h2f(xh[(size_t)r1 * 64 + lane]);
        float2 f2 = h2f(xh[(size_t)r2 * 64 + lane]);
        float2 f3 = h2f(xh[(size_t)r3 * 64 + lane]);
        accx += v0 * f0.x + v1 * f1.x + v2 * f2.x + v3 * f3.x;
        accy += v0 * f0.y + v1 * f1.y + v2 * f2.y + v3 * f3.y;
    }
    for (; i < n; i++) {
        unsigned v0u = (unsigned)__shfl(eh, i);
        int r0 = v0u & 0xFFFF;
        float v0 = hu2f((unsigned short)(v0u >> 16));
        float2 f0 = h2f(xh[(size_t)r0 * 64 + lane]);
        accx += v0 * f0.x;
        accy += v0 * f0.y;
    }

    float2 b = ((const float2*)bias)[lane];
    float ox = fmaxf(dv * accx + b.x, 0.0f);
    float oy = fmaxf(dv * accy + b.y, 0.0f);
    ((unsigned int*)outh)[(size_t)node * 64 + lane] = f2h(ox, oy);
}

// ---------------------------------------------------------------------------
// Pool (fp16 in): grid = graph x slice; unroll-4 ILP; LDS reduce; atomics.
// ---------------------------------------------------------------------------
__global__ __launch_bounds__(256) void pool_kernel(const __half* __restrict__ h,
                                                   const int* __restrict__ gstart,
                                                   float* __restrict__ pooled) {
    int g = blockIdx.x >> 3;
    int s = blockIdx.x & (POOL_SPLIT - 1);
    int a = gstart[g], b = gstart[g + 1];
    int len = b - a;
    int lo = a + (int)((long long)len * s / POOL_SPLIT);
    int hi = a + (int)((long long)len * (s + 1) / POOL_SPLIT);

    int d2 = threadIdx.x & 63;
    int nl = threadIdx.x >> 6;
    const unsigned int* h2 = (const unsigned int*)h;

    float accx = 0.0f, accy = 0.0f;
    int n = lo + nl;
    for (; n + 12 < hi; n += 16) {
        float2 v0 = h2f(h2[(size_t)n * 64 + d2]);
        float2 v1 = h2f(h2[(size_t)(n + 4) * 64 + d2]);
        float2 v2 = h2f(h2[(size_t)(n + 8) * 64 + d2]);
        float2 v3 = h2f(h2[(size_t)(n + 12) * 64 + d2]);
        accx += (v0.x + v1.x) + (v2.x + v3.x);
        accy += (v0.y + v1.y) + (v2.y + v3.y);
    }
    for (; n < hi; n += 4) {
        float2 v = h2f(h2[(size_t)n * 64 + d2]);
        accx += v.x; accy += v.y;
    }

    __shared__ float red[4][128];
    red[nl][d2 * 2]     = accx;
    red[nl][d2 * 2 + 1] = accy;
    __syncthreads();
    if (threadIdx.x < 128) {
        float v = red[0][threadIdx.x] + red[1][threadIdx.x]
                + red[2][threadIdx.x] + red[3][threadIdx.x];
        atomicAdd(&pooled[(size_t)g * 128 + threadIdx.x], v);
    }
}

__global__ __launch_bounds__(64) void final_kernel(const float* __restrict__ pooled,
                                                   const int* __restrict__ gstart,
                                                   const float* __restrict__ Wh,
                                                   const float* __restrict__ bh,
                                                   float* __restrict__ out) {
    int g = blockIdx.x;
    int t = threadIdx.x;
    float v = pooled[(size_t)g * 128 + t] * Wh[t]
            + pooled[(size_t)g * 128 + 64 + t] * Wh[64 + t];
#pragma unroll
    for (int off = 32; off > 0; off >>= 1) v += __shfl_down(v, off, 64);
    if (t == 0) {
        float cntf = (float)(gstart[g + 1] - gstart[g]);
        out[g] = v / fmaxf(cntf, 1.0f) + bh[0];
    }
}

// ---------------------------------------------------------------------------
extern "C" void kernel_launch(void* const* d_in, const int* in_sizes, int n_in,
                              void* d_out, int out_size, void* d_ws, size_t ws_size,
                              hipStream_t stream) {
    const float* x   = (const float*)d_in[0];
    const float* ew  = (const float*)d_in[1];
    const float* W1  = (const float*)d_in[2];
    const float* b1  = (const float*)d_in[3];
    const float* W2  = (const float*)d_in[4];
    const float* b2  = (const float*)d_in[5];
    const float* Wh  = (const float*)d_in[6];
    const float* bh  = (const float*)d_in[7];
    const int*   ei  = (const int*)d_in[8];
    const int*   bat = (const int*)d_in[9];
    float* out = (float*)d_out;

    char* ws = (char*)d_ws;
    __half* bufAh  = (__half*)ws;                         ws += (size_t)N_NODES * D * 2;
    __half* bufBh  = (__half*)ws;                         ws += (size_t)N_NODES * D * 2;
    unsigned int* bucket = (unsigned int*)ws;             ws += (size_t)N_NODES * CAP * 4;
    unsigned long long* packed = (unsigned long long*)ws; ws += (size_t)N_NODES * 8;
    float*  dinv   = (float*)ws;                          ws += (size_t)N_NODES * 4;
    int*    cnt    = (int*)ws;                            ws += (size_t)N_NODES * 4;
    int*    gstart = (int*)ws;                            ws += (N_GRAPHS + 1) * 4;
    float*  pooled = (float*)ws;                          ws += (size_t)N_GRAPHS * D * 4;

    const int nb_nodes = (N_NODES + 255) / 256;       // 196
    const int nb_gemm  = (N_NODES + 127) / 128;       // 391
    const int nb_agg   = N_NODES / 4;                 // 12500 (exact)
    const int nb_scale = N_NODES * 64 / 256;          // 12500 (exact)
    const int nb_pool  = N_GRAPHS * POOL_SPLIT;       // 512

    // --- zero counters / pool accumulator ---
    hipMemsetAsync(packed, 0, (size_t)N_NODES * 8, stream);
    hipMemsetAsync(pooled, 0, (size_t)N_GRAPHS * D * 4, stream);

    // --- fused: gemm1 (x@W1 -> fp16, BK=32) overlapped with fill ---
    fused_gemm1_fill<<<NB_GEMM1 + NB_FILL, 256, 0, stream>>>(x, W1, bufAh, ei, ew, packed, bucket);

    // --- unpack (196 blocks) + coalesced prescale (12500 blocks) ---
    dinv_gstart_kernel<<<nb_nodes, 256, 0, stream>>>(packed, cnt, dinv, bat, gstart);
    scale_kernel<<<nb_scale, 256, 0, stream>>>((unsigned int*)bufAh, dinv);

    // --- layer 1 agg ---
    agg_bucket_kernel<<<nb_agg, 256, 0, stream>>>(bufAh, cnt, bucket, dinv, b1, bufBh);

    // --- layer 2 ---
    gemm128h2<<<nb_gemm, 256, 0, stream>>>(bufBh, W2, dinv, bufAh);
    agg_bucket_kernel<<<nb_agg, 256, 0, stream>>>(bufAh, cnt, bucket, dinv, b2, bufBh);

    // --- pool + head ---
    pool_kernel<<<nb_pool, 256, 0, stream>>>(bufBh, gstart, pooled);
    final_kernel<<<N_GRAPHS, 64, 0, stream>>>(pooled, gstart, Wh, bh, out);
}

// Round 12
// 228.546 us; speedup vs baseline: 1.7564x; 1.1145x over previous
//
#include <hip/hip_runtime.h>
#include <hip/hip_bf16.h>
#include <hip/hip_fp16.h>

#define N_NODES  50000
#define N_EDGES  800000
#define D        128
#define N_GRAPHS 64
#define CAP      64          // bucket capacity; in-deg ~ Poisson(16), P(>=64) ~ 1e-19
#define EW_SCALE 1048576.0f  // 2^20 fixed-point for packed weighted-degree
#define NB_GEMM1 391         // ceil(50000/128)
#define NB_FILL  3125        // 800000/256

typedef _Float16 half8 __attribute__((ext_vector_type(8)));
typedef float   float4v __attribute__((ext_vector_type(4)));

__device__ __forceinline__ float2 h2f(unsigned int u) {
    __half2 h = *reinterpret_cast<__half2*>(&u);
    return __half22float2(h);
}
__device__ __forceinline__ unsigned int f2h(float a, float b) {
    __half2 h = __floats2half2_rn(a, b);
    return *reinterpret_cast<unsigned int*>(&h);
}
__device__ __forceinline__ float hu2f(unsigned short u) {
    __half_raw hr; hr.x = u;
    return __half2float(__half(hr));
}

// ---------------------------------------------------------------------------
// FUSED: blocks [0,391) = gemm1 (fp32 x @ W1 -> fp16, BK=32, LDS=32KB);
//        blocks [391,3516) = fill (1 edge/thread, returning 64-bit atomic
//        on 50K spread counters). Bucket entry 4B: src:u16 | ew:fp16.
// ---------------------------------------------------------------------------
__global__ __launch_bounds__(256) void fused_gemm1_fill(const float* __restrict__ X,
                                                        const float* __restrict__ W,
                                                        __half* __restrict__ Yh,
                                                        const int* __restrict__ ei,
                                                        const float* __restrict__ ew,
                                                        unsigned long long* __restrict__ packed,
                                                        unsigned int* __restrict__ bucket) {
    __shared__ float XT[32 * 128];  // 16 KB
    __shared__ float Ws[32 * 128];  // 16 KB

    if (blockIdx.x >= NB_GEMM1) {
        int e = (blockIdx.x - NB_GEMM1) * 256 + threadIdx.x;
        if (e >= N_EDGES) return;
        int r = ei[e];
        int c = ei[N_EDGES + e];
        float w = ew[e];
        unsigned long long add = (1ULL << 40) | (unsigned long long)(unsigned)(w * EW_SCALE + 0.5f);
        unsigned long long old = atomicAdd(&packed[c], add);
        unsigned pos = (unsigned)(old >> 40);
        if (pos < CAP) {
            unsigned short wh = __half_as_ushort(__float2half_rn(w));
            bucket[(size_t)c * CAP + pos] = (unsigned)r | ((unsigned)wh << 16);
        }
        return;
    }

    const int tid  = threadIdx.x;
    const int row0 = blockIdx.x * 128;
    const int tr = tid >> 4, tc = tid & 15;
    float acc[8][8] = {};

    for (int kt = 0; kt < 4; kt++) {
        const int kbase = kt * 32;
        {
            const float4* src = (const float4*)(W + kbase * 128);
            float4* dst = (float4*)Ws;
            for (int i = tid; i < 1024; i += 256) dst[i] = src[i];
        }
        {
            int r  = tid >> 1;
            int rr = row0 + r; if (rr >= N_NODES) rr = N_NODES - 1;
            int k0 = (tid & 1) * 16;
            const float4* src = (const float4*)(X + (size_t)rr * 128 + kbase + k0);
#pragma unroll
            for (int i = 0; i < 4; i++) {
                float4 v = src[i];
                int k = k0 + i * 4;
                XT[(k + 0) * 128 + r] = v.x;
                XT[(k + 1) * 128 + r] = v.y;
                XT[(k + 2) * 128 + r] = v.z;
                XT[(k + 3) * 128 + r] = v.w;
            }
        }
        __syncthreads();
#pragma unroll 4
        for (int k = 0; k < 32; k++) {
            float xs[8], ws[8];
            *(float4*)&xs[0] = *(const float4*)(XT + k * 128 + tr * 8);
            *(float4*)&xs[4] = *(const float4*)(XT + k * 128 + tr * 8 + 4);
            *(float4*)&ws[0] = *(const float4*)(Ws + k * 128 + tc * 8);
            *(float4*)&ws[4] = *(const float4*)(Ws + k * 128 + tc * 8 + 4);
#pragma unroll
            for (int i = 0; i < 8; i++)
#pragma unroll
                for (int j = 0; j < 8; j++)
                    acc[i][j] += xs[i] * ws[j];
        }
        __syncthreads();
    }
#pragma unroll
    for (int i = 0; i < 8; i++) {
        int r = row0 + tr * 8 + i;
        if (r < N_NODES) {
            uint4 p;
            p.x = f2h(acc[i][0], acc[i][1]);
            p.y = f2h(acc[i][2], acc[i][3]);
            p.z = f2h(acc[i][4], acc[i][5]);
            p.w = f2h(acc[i][6], acc[i][7]);
            *(uint4*)(Yh + (size_t)r * 128 + tc * 8) = p;
        }
    }
}

// ---------------------------------------------------------------------------
// unpack cnt/dinv + graph starts from sorted batch
// ---------------------------------------------------------------------------
__global__ void dinv_gstart_kernel(const unsigned long long* __restrict__ packed,
                                   int* __restrict__ cnt, float* __restrict__ dinv,
                                   const int* __restrict__ batch, int* __restrict__ gstart) {
    int i = blockIdx.x * 256 + threadIdx.x;
    if (i >= N_NODES) return;
    unsigned long long p = packed[i];
    int c = (int)(p >> 40);
    cnt[i] = c < CAP ? c : CAP;
    float deg = 1.0f + (float)(p & 0xFFFFFFFFFFULL) * (1.0f / EW_SCALE);
    dinv[i] = rsqrtf(deg);

    int a = batch[i];
    if (i == 0) {
        for (int g = 0; g <= a; g++) gstart[g] = 0;
    } else {
        int pg = batch[i - 1];
        for (int g = pg + 1; g <= a; g++) gstart[g] = i;
    }
    if (i == N_NODES - 1) {
        for (int g = a + 1; g <= N_GRAPHS; g++) gstart[g] = N_NODES;
    }
}

// x' = dinv[node] * x (fp16 in place, coalesced half2/thread, 12500 blocks)
__global__ __launch_bounds__(256) void scale_kernel(unsigned int* __restrict__ xh,
                                                    const float* __restrict__ dinv) {
    int idx = blockIdx.x * 256 + threadIdx.x;   // covers exactly N_NODES*64
    float dv = dinv[idx >> 6];
    float2 f = h2f(xh[idx]);
    xh[idx] = f2h(f.x * dv, f.y * dv);
}

// ---------------------------------------------------------------------------
// gemm2 via MFMA fp16: Y = X(fp16) @ W(fp32->fp16 in-reg), epilogue *dinv.
// One wave per 16x128 row strip. Layouts (verified docs):
//   A[m=lane&15][k=quad*8+j]; B[k=quad*8+j][n=lane&15]; D[row=quad*4+r][col=lane&15]
// ---------------------------------------------------------------------------
__global__ __launch_bounds__(256) void gemm2_mfma(const __half* __restrict__ Xh,
                                                  const float* __restrict__ W,
                                                  const float* __restrict__ dinv,
                                                  __half* __restrict__ Yh) {
    const int wv   = threadIdx.x >> 6;
    const int lane = threadIdx.x & 63;
    const int quad = lane >> 4;
    const int l16  = lane & 15;
    const int row0 = blockIdx.x * 64 + wv * 16;
    if (row0 >= N_NODES) return;          // tail block: 50000 = 781*64 + 16

    float4v acc[8] = {};

#pragma unroll
    for (int kc = 0; kc < 4; kc++) {
        const int k0 = kc * 32;
        half8 a = *(const half8*)(Xh + (size_t)(row0 + l16) * 128 + k0 + quad * 8);
#pragma unroll
        for (int ct = 0; ct < 8; ct++) {
            const float* wp = W + (size_t)(k0 + quad * 8) * 128 + ct * 16 + l16;
            half8 b;
#pragma unroll
            for (int j = 0; j < 8; j++) b[j] = (_Float16)wp[j * 128];
            acc[ct] = __builtin_amdgcn_mfma_f32_16x16x32_f16(a, b, acc[ct], 0, 0, 0);
        }
    }

#pragma unroll
    for (int r = 0; r < 4; r++) {
        int row = row0 + quad * 4 + r;
        float s = dinv[row];
#pragma unroll
        for (int ct = 0; ct < 8; ct++) {
            Yh[(size_t)row * 128 + ct * 16 + l16] = __float2half_rn(acc[ct][r] * s);
        }
    }
}

// ---------------------------------------------------------------------------
// Layer-1 aggregation on pre-scaled x' (fp16 in/out):
//   out[c] = relu( dinv[c]*(x'[c] + sum ew_i * x'[src_i]) + b )
// ---------------------------------------------------------------------------
__global__ __launch_bounds__(256) void agg_bucket_kernel(const __half* __restrict__ xwh,
                                                         const int* __restrict__ cnt,
                                                         const unsigned int* __restrict__ bucket,
                                                         const float* __restrict__ dinv,
                                                         const float* __restrict__ bias,
                                                         __half* __restrict__ outh) {
    int node = blockIdx.x * 4 + (threadIdx.x >> 6);
    int lane = threadIdx.x & 63;
    const unsigned int* xh = (const unsigned int*)xwh;

    float dv = dinv[node];
    int n = cnt[node];

    unsigned int ehdr = (lane < n) ? bucket[(size_t)node * CAP + lane] : 0u;
    int eh = (int)ehdr;

    float2 xs = h2f(xh[(size_t)node * 64 + lane]);
    float accx = xs.x;
    float accy = xs.y;

    int i = 0;
    for (; i + 3 < n; i += 4) {
        unsigned v0u = (unsigned)__shfl(eh, i);
        unsigned v1u = (unsigned)__shfl(eh, i + 1);
        unsigned v2u = (unsigned)__shfl(eh, i + 2);
        unsigned v3u = (unsigned)__shfl(eh, i + 3);
        int r0 = v0u & 0xFFFF, r1 = v1u & 0xFFFF, r2 = v2u & 0xFFFF, r3 = v3u & 0xFFFF;
        float v0 = hu2f((unsigned short)(v0u >> 16));
        float v1 = hu2f((unsigned short)(v1u >> 16));
        float v2 = hu2f((unsigned short)(v2u >> 16));
        float v3 = hu2f((unsigned short)(v3u >> 16));
        float2 f0 = h2f(xh[(size_t)r0 * 64 + lane]);
        float2 f1 = h2f(xh[(size_t)r1 * 64 + lane]);
        float2 f2 = h2f(xh[(size_t)r2 * 64 + lane]);
        float2 f3 = h2f(xh[(size_t)r3 * 64 + lane]);
        accx += v0 * f0.x + v1 * f1.x + v2 * f2.x + v3 * f3.x;
        accy += v0 * f0.y + v1 * f1.y + v2 * f2.y + v3 * f3.y;
    }
    for (; i < n; i++) {
        unsigned v0u = (unsigned)__shfl(eh, i);
        int r0 = v0u & 0xFFFF;
        float v0 = hu2f((unsigned short)(v0u >> 16));
        float2 f0 = h2f(xh[(size_t)r0 * 64 + lane]);
        accx += v0 * f0.x;
        accy += v0 * f0.y;
    }

    float2 b = ((const float2*)bias)[lane];
    float ox = fmaxf(dv * accx + b.x, 0.0f);
    float oy = fmaxf(dv * accy + b.y, 0.0f);
    ((unsigned int*)outh)[(size_t)node * 64 + lane] = f2h(ox, oy);
}

// ---------------------------------------------------------------------------
// Layer-2 aggregation FUSED with head dot: nodedot[c] = relu(h2[c]) . Wh
// (head is linear in the pool, so pool/final reduce nodedot instead of h2).
// ---------------------------------------------------------------------------
__global__ __launch_bounds__(256) void agg_head_kernel(const __half* __restrict__ xwh,
                                                       const int* __restrict__ cnt,
                                                       const unsigned int* __restrict__ bucket,
                                                       const float* __restrict__ dinv,
                                                       const float* __restrict__ bias,
                                                       const float* __restrict__ Wh,
                                                       float* __restrict__ nodedot) {
    int node = blockIdx.x * 4 + (threadIdx.x >> 6);
    int lane = threadIdx.x & 63;
    const unsigned int* xh = (const unsigned int*)xwh;

    float dv = dinv[node];
    int n = cnt[node];

    unsigned int ehdr = (lane < n) ? bucket[(size_t)node * CAP + lane] : 0u;
    int eh = (int)ehdr;

    float2 xs = h2f(xh[(size_t)node * 64 + lane]);
    float accx = xs.x;
    float accy = xs.y;

    int i = 0;
    for (; i + 3 < n; i += 4) {
        unsigned v0u = (unsigned)__shfl(eh, i);
        unsigned v1u = (unsigned)__shfl(eh, i + 1);
        unsigned v2u = (unsigned)__shfl(eh, i + 2);
        unsigned v3u = (unsigned)__shfl(eh, i + 3);
        int r0 = v0u & 0xFFFF, r1 = v1u & 0xFFFF, r2 = v2u & 0xFFFF, r3 = v3u & 0xFFFF;
        float v0 = hu2f((unsigned short)(v0u >> 16));
        float v1 = hu2f((unsigned short)(v1u >> 16));
        float v2 = hu2f((unsigned short)(v2u >> 16));
        float v3 = hu2f((unsigned short)(v3u >> 16));
        float2 f0 = h2f(xh[(size_t)r0 * 64 + lane]);
        float2 f1 = h2f(xh[(size_t)r1 * 64 + lane]);
        float2 f2 = h2f(xh[(size_t)r2 * 64 + lane]);
        float2 f3 = h2f(xh[(size_t)r3 * 64 + lane]);
        accx += v0 * f0.x + v1 * f1.x + v2 * f2.x + v3 * f3.x;
        accy += v0 * f0.y + v1 * f1.y + v2 * f2.y + v3 * f3.y;
    }
    for (; i < n; i++) {
        unsigned v0u = (unsigned)__shfl(eh, i);
        int r0 = v0u & 0xFFFF;
        float v0 = hu2f((unsigned short)(v0u >> 16));
        float2 f0 = h2f(xh[(size_t)r0 * 64 + lane]);
        accx += v0 * f0.x;
        accy += v0 * f0.y;
    }

    float2 b = ((const float2*)bias)[lane];
    float hx = fmaxf(dv * accx + b.x, 0.0f);
    float hy = fmaxf(dv * accy + b.y, 0.0f);
    float2 w = ((const float2*)Wh)[lane];
    float s = hx * w.x + hy * w.y;
#pragma unroll
    for (int off = 32; off > 0; off >>= 1) s += __shfl_down(s, off, 64);
    if (lane == 0) nodedot[node] = s;
}

// out[g] = (sum nodedot over graph) / cnt + bh
__global__ __launch_bounds__(256) void final2_kernel(const float* __restrict__ nodedot,
                                                     const int* __restrict__ gstart,
                                                     const float* __restrict__ bh,
                                                     float* __restrict__ out) {
    __shared__ float red[256];
    int g = blockIdx.x;
    int a = gstart[g], b = gstart[g + 1];
    float s = 0.0f;
    for (int n = a + threadIdx.x; n < b; n += 256) s += nodedot[n];
    red[threadIdx.x] = s;
    __syncthreads();
#pragma unroll
    for (int off = 128; off > 0; off >>= 1) {
        if (threadIdx.x < off) red[threadIdx.x] += red[threadIdx.x + off];
        __syncthreads();
    }
    if (threadIdx.x == 0)
        out[g] = red[0] / fmaxf((float)(b - a), 1.0f) + bh[0];
}

// ---------------------------------------------------------------------------
extern "C" void kernel_launch(void* const* d_in, const int* in_sizes, int n_in,
                              void* d_out, int out_size, void* d_ws, size_t ws_size,
                              hipStream_t stream) {
    const float* x   = (const float*)d_in[0];
    const float* ew  = (const float*)d_in[1];
    const float* W1  = (const float*)d_in[2];
    const float* b1  = (const float*)d_in[3];
    const float* W2  = (const float*)d_in[4];
    const float* b2  = (const float*)d_in[5];
    const float* Wh  = (const float*)d_in[6];
    const float* bh  = (const float*)d_in[7];
    const int*   ei  = (const int*)d_in[8];
    const int*   bat = (const int*)d_in[9];
    float* out = (float*)d_out;

    char* ws = (char*)d_ws;
    __half* bufAh  = (__half*)ws;                         ws += (size_t)N_NODES * D * 2;
    __half* bufBh  = (__half*)ws;                         ws += (size_t)N_NODES * D * 2;
    unsigned int* bucket = (unsigned int*)ws;             ws += (size_t)N_NODES * CAP * 4;
    unsigned long long* packed = (unsigned long long*)ws; ws += (size_t)N_NODES * 8;
    float*  dinv    = (float*)ws;                         ws += (size_t)N_NODES * 4;
    int*    cnt     = (int*)ws;                           ws += (size_t)N_NODES * 4;
    int*    gstart  = (int*)ws;                           ws += (N_GRAPHS + 1) * 4;
    float*  nodedot = (float*)ws;                         ws += (size_t)N_NODES * 4;

    const int nb_nodes = (N_NODES + 255) / 256;       // 196
    const int nb_agg   = N_NODES / 4;                 // 12500 (exact)
    const int nb_scale = N_NODES * 64 / 256;          // 12500 (exact)
    const int nb_gemm2 = (N_NODES + 63) / 64;         // 782

    hipMemsetAsync(packed, 0, (size_t)N_NODES * 8, stream);

    // gemm1 (x@W1 -> fp16) overlapped with fill (atomic-floor-bound)
    fused_gemm1_fill<<<NB_GEMM1 + NB_FILL, 256, 0, stream>>>(x, W1, bufAh, ei, ew, packed, bucket);

    dinv_gstart_kernel<<<nb_nodes, 256, 0, stream>>>(packed, cnt, dinv, bat, gstart);
    scale_kernel<<<nb_scale, 256, 0, stream>>>((unsigned int*)bufAh, dinv);

    // layer 1
    agg_bucket_kernel<<<nb_agg, 256, 0, stream>>>(bufAh, cnt, bucket, dinv, b1, bufBh);

    // layer 2 (MFMA gemm, dinv folded) + fused head dot
    gemm2_mfma<<<nb_gemm2, 256, 0, stream>>>(bufBh, W2, dinv, bufAh);
    agg_head_kernel<<<nb_agg, 256, 0, stream>>>(bufAh, cnt, bucket, dinv, b2, Wh, nodedot);

    // segment-sum + head bias
    final2_kernel<<<N_GRAPHS, 256, 0, stream>>>(nodedot, gstart, bh, out);
}